// Round 3
// baseline (10187.674 us; speedup 1.0000x reference)
//
#include <hip/hip_runtime.h>

typedef unsigned short u16;
typedef unsigned int   u32;
typedef __attribute__((ext_vector_type(8))) short bf16x8;
typedef __attribute__((ext_vector_type(4))) float f32x4;

#define NB 64
#define TT 256
#define FF 1024
#define HH 1024
#define KK 2048
#define GG 4096
#define NBLK 256

// ws layout in u16 units
#define WPACK_SZ  (KK*GG)                    // 8388608 u16 = 16 MB
#define XPACK_SZ  ((size_t)NB*TT*FF)         // 16777216 u16 = 32 MB
#define HPACK_SZ  (2*4*32*64*8)              // 131072 u16 = 256 KB (double buffer)
#define FLAGS_SZ  (NBLK*16)                  // u32 units: 256 flags, 64B apart

__device__ __forceinline__ u16 f2bf(float f) {
  u32 u = __float_as_uint(f);
  u32 r = (u + 0x7FFFu + ((u >> 16) & 1u)) >> 16;
  return (u16)r;
}

// Pack W [K=2048][G=4096] fp32 -> B-fragment order:
// wp[((ct*64 + kt)*64 + l)*8 + j] = bf16( W[kt*32 + (l>>4)*8 + j][ct*16 + (l&15)] )
__global__ void pack_w(const float* __restrict__ W, u16* __restrict__ wp) {
  int tid = blockIdx.x * blockDim.x + threadIdx.x;   // 524288 threads
  if (tid >= (KK * GG / 16)) return;
  int j  = tid & 7;
  int g  = (tid >> 3) & 3;
  int kt = (tid >> 5) & 63;
  int ct = tid >> 11;                                // 0..255
  int k  = kt * 32 + g * 8 + j;
  const float* src = W + (size_t)k * GG + ct * 16;
  u16* dst = wp + (size_t)(ct * 64 + kt) * 512 + j;
  float4 v0 = *(const float4*)(src + 0);
  float4 v1 = *(const float4*)(src + 4);
  float4 v2 = *(const float4*)(src + 8);
  float4 v3 = *(const float4*)(src + 12);
  float vv[16] = {v0.x,v0.y,v0.z,v0.w, v1.x,v1.y,v1.z,v1.w,
                  v2.x,v2.y,v2.z,v2.w, v3.x,v3.y,v3.z,v3.w};
  #pragma unroll
  for (int c = 0; c < 16; ++c) dst[(size_t)(g * 16 + c) * 8] = f2bf(vv[c]);
}

// Pack x [N][T][F] fp32 -> A-fragment order per (t, rt):
// xp[(((t*4 + rt)*32 + kt)*64 + l)*8 + j] = bf16( x[16rt + (l&15)][t][kt*32 + (l>>4)*8 + j] )
__global__ void pack_x(const float* __restrict__ X, u16* __restrict__ xp) {
  int tid = blockIdx.x * blockDim.x + threadIdx.x;   // 2097152 threads
  if (tid >= (int)(NB * TT * FF / 8)) return;
  int l  = tid & 63;
  int kt = (tid >> 6) & 31;
  int rt = (tid >> 11) & 3;
  int t  = tid >> 13;                                // 0..255
  int n  = rt * 16 + (l & 15);
  int f  = kt * 32 + (l >> 4) * 8;
  const float* src = X + (size_t)n * TT * FF + (size_t)t * FF + f;
  float4 a = *(const float4*)(src);
  float4 b = *(const float4*)(src + 4);
  u16 tmp[8] = { f2bf(a.x), f2bf(a.y), f2bf(a.z), f2bf(a.w),
                 f2bf(b.x), f2bf(b.y), f2bf(b.z), f2bf(b.w) };
  *(uint4*)(xp + (size_t)((t * 4 + rt) * 32 + kt) * 512 + l * 8) = *(uint4*)tmp;
}

// zero the h double-buffer and the barrier flags (ws is poisoned 0xAA)
__global__ void init_state(u32* __restrict__ hp32, u32* __restrict__ flags) {
  int tid = blockIdx.x * blockDim.x + threadIdx.x;   // 65536 threads
  if (tid < HPACK_SZ / 2) hp32[tid] = 0u;
  if (tid < FLAGS_SZ)     flags[tid] = 0u;
}

__launch_bounds__(256, 1)
__global__ void lstm_main(const u16* __restrict__ wp, const u16* __restrict__ xp,
                          u16* __restrict__ hp, const float* __restrict__ bias,
                          float* __restrict__ z, float* __restrict__ hout,
                          float* __restrict__ memout, u32* flags) {
  const int b   = blockIdx.x;        // 256 blocks (<= 256 CUs -> all co-resident)
  const int cgi = b & 63;            // col-group: 16 h-cols
  const int rt  = b >> 6;            // row-tile: 16 batch rows
  const int w   = threadIdx.x >> 6;  // wave = gate index 0..3
  const int l   = threadIdx.x & 63;
  const int ct  = w * 64 + cgi;      // global col-tile 0..255

  const u16* bp = wp + (size_t)ct * 32768 + l * 8;   // 64 kt * 512 per col-tile
  const float bv = bias[ct * 16 + (l & 15)];

  __shared__ float gl[4][16][16];

  const int tid = threadIdx.x;
  const int er  = tid >> 4;          // 0..15 epilogue row
  const int ec  = tid & 15;          // 0..15 epilogue col
  const int m   = rt * 16 + er;      // batch row
  const int col = cgi * 16 + ec;     // col within gate [0,1024)
  // hpack write slot for (m, col)
  const int kt2 = col >> 5;
  const int g2  = (col >> 3) & 3;
  const int jj  = col & 7;
  const int l2  = er | (g2 << 4);

  float memv = 0.0f;                 // cell state lives in a register

  for (int t = 0; t < TT; ++t) {
    const int p = t & 1;
    const u16* ax = xp + (size_t)((t * 4 + rt) * 32) * 512 + l * 8;
    const u16* ah = hp + (size_t)((p * 4 + rt) * 32) * 512 + l * 8;

    f32x4 acc0 = {bv, bv, bv, bv};
    f32x4 acc1 = {0.f, 0.f, 0.f, 0.f};
    #pragma unroll
    for (int kt = 0; kt < 32; kt += 2) {
      bf16x8 a0 = *(const bf16x8*)(ax + (size_t)kt * 512);
      bf16x8 b0 = *(const bf16x8*)(bp + (size_t)kt * 512);
      bf16x8 a1 = *(const bf16x8*)(ax + (size_t)(kt + 1) * 512);
      bf16x8 b1 = *(const bf16x8*)(bp + (size_t)(kt + 1) * 512);
      acc0 = __builtin_amdgcn_mfma_f32_16x16x32_bf16(a0, b0, acc0, 0, 0, 0);
      acc1 = __builtin_amdgcn_mfma_f32_16x16x32_bf16(a1, b1, acc1, 0, 0, 0);
    }
    #pragma unroll
    for (int kt = 0; kt < 32; kt += 2) {
      bf16x8 a0 = *(const bf16x8*)(ah + (size_t)kt * 512);
      bf16x8 b0 = *(const bf16x8*)(bp + (size_t)(32 + kt) * 512);
      bf16x8 a1 = *(const bf16x8*)(ah + (size_t)(kt + 1) * 512);
      bf16x8 b1 = *(const bf16x8*)(bp + (size_t)(32 + kt + 1) * 512);
      acc0 = __builtin_amdgcn_mfma_f32_16x16x32_bf16(a0, b0, acc0, 0, 0, 0);
      acc1 = __builtin_amdgcn_mfma_f32_16x16x32_bf16(a1, b1, acc1, 0, 0, 0);
    }

    // C-layout: col = l&15, row = (l>>4)*4 + r  (HW-verified)
    #pragma unroll
    for (int r = 0; r < 4; ++r)
      gl[w][(l >> 4) * 4 + r][l & 15] = acc0[r] + acc1[r];
    __syncthreads();

    // gate combine: one (m,col) element per thread
    float ai = gl[0][er][ec], af = gl[1][er][ec];
    float ao = gl[2][er][ec], ag = gl[3][er][ec];
    float si = 1.f / (1.f + __expf(-ai));
    float sf = 1.f / (1.f + __expf(-af));
    float so = 1.f / (1.f + __expf(-ao));
    float tg = 1.f - 2.f / (__expf(2.f * ag) + 1.f);   // safe tanh
    memv = sf * memv + si * tg;
    float th = 1.f - 2.f / (__expf(2.f * memv) + 1.f); // safe tanh
    float h = so * th;

    z[((size_t)m * TT + t) * HH + col] = h;
    hp[(size_t)(((p ^ 1) * 4 + rt) * 32 + kt2) * 512 + l2 * 8 + jj] = f2bf(h);
    if (t == TT - 1) {
      hout[(size_t)m * HH + col] = h;
      break;                         // no barrier needed after the last step
    }

    // ---- distributed grid barrier: no RMW, one flag line per block ----
    __syncthreads();                 // all block stores drained (vmcnt) to L2
    const u32 tgt = (u32)(t + 1);
    if (tid == 0) {
      __threadfence();               // release: L2 writeback -> h agent-visible
      __hip_atomic_store(&flags[b * 16], tgt, __ATOMIC_RELEASE,
                         __HIP_MEMORY_SCOPE_AGENT);
    }
    // each of the 256 threads watches one block's flag (independent lines)
    while (__hip_atomic_load(&flags[tid * 16], __ATOMIC_RELAXED,
                             __HIP_MEMORY_SCOPE_AGENT) < tgt)
      __builtin_amdgcn_s_sleep(2);
    __syncthreads();
    __threadfence();                 // acquire: invalidate caches before h reads
  }
  memout[(size_t)m * HH + col] = memv;
}

extern "C" void kernel_launch(void* const* d_in, const int* in_sizes, int n_in,
                              void* d_out, int out_size, void* d_ws, size_t ws_size,
                              hipStream_t stream) {
  const float* x    = (const float*)d_in[0];
  const float* W    = (const float*)d_in[1];
  const float* bias = (const float*)d_in[2];

  float* z      = (float*)d_out;
  float* hout   = z + (size_t)NB * TT * HH;
  float* memout = hout + (size_t)NB * HH;

  u16* wp = (u16*)d_ws;
  u16* xp = wp + WPACK_SZ;
  u16* hp = xp + XPACK_SZ;
  u32* flags = (u32*)(hp + HPACK_SZ);

  hipLaunchKernelGGL(pack_w, dim3(2048), dim3(256), 0, stream, W, wp);
  hipLaunchKernelGGL(pack_x, dim3(8192), dim3(256), 0, stream, x, xp);
  hipLaunchKernelGGL(init_state, dim3(256), dim3(256), 0, stream, (u32*)hp, flags);

  hipLaunchKernelGGL(lstm_main, dim3(NBLK), dim3(256), 0, stream,
                     wp, xp, hp, bias, z, hout, memout, flags);
}

// Round 4
// 6185.162 us; speedup vs baseline: 1.6471x; 1.6471x over previous
//
#include <hip/hip_runtime.h>

typedef unsigned short u16;
typedef unsigned int   u32;
typedef __attribute__((ext_vector_type(8))) short bf16x8;
typedef __attribute__((ext_vector_type(4))) float f32x4;

#define NB 64
#define TT 256
#define FF 1024
#define HH 1024
#define KK 2048
#define GG 4096
#define NBLK 256

// ws layout in u16 units
#define WPACK_SZ  (KK*GG)                    // 8388608 u16 = 16 MB
#define XPACK_SZ  ((size_t)NB*TT*FF)         // 16777216 u16 = 32 MB
#define HPACK_SZ  (2*4*32*64*8)              // 131072 u16 = 256 KB (double buffer)
#define FLAGS_SZ  (4*64*4)                   // u32: 4 rt-groups x 64 flags, 16B stride

__device__ __forceinline__ u16 f2bf(float f) {
  u32 u = __float_as_uint(f);
  u32 r = (u + 0x7FFFu + ((u >> 16) & 1u)) >> 16;
  return (u16)r;
}

// Pack W [K=2048][G=4096] fp32 -> B-fragment order:
// wp[((ct*64 + kt)*64 + l)*8 + j] = bf16( W[kt*32 + (l>>4)*8 + j][ct*16 + (l&15)] )
__global__ void pack_w(const float* __restrict__ W, u16* __restrict__ wp) {
  int tid = blockIdx.x * blockDim.x + threadIdx.x;   // 524288 threads
  if (tid >= (KK * GG / 16)) return;
  int j  = tid & 7;
  int g  = (tid >> 3) & 3;
  int kt = (tid >> 5) & 63;
  int ct = tid >> 11;                                // 0..255
  int k  = kt * 32 + g * 8 + j;
  const float* src = W + (size_t)k * GG + ct * 16;
  u16* dst = wp + (size_t)(ct * 64 + kt) * 512 + j;
  float4 v0 = *(const float4*)(src + 0);
  float4 v1 = *(const float4*)(src + 4);
  float4 v2 = *(const float4*)(src + 8);
  float4 v3 = *(const float4*)(src + 12);
  float vv[16] = {v0.x,v0.y,v0.z,v0.w, v1.x,v1.y,v1.z,v1.w,
                  v2.x,v2.y,v2.z,v2.w, v3.x,v3.y,v3.z,v3.w};
  #pragma unroll
  for (int c = 0; c < 16; ++c) dst[(size_t)(g * 16 + c) * 8] = f2bf(vv[c]);
}

// Pack x [N][T][F] fp32 -> A-fragment order per (t, rt):
// xp[(((t*4 + rt)*32 + kt)*64 + l)*8 + j] = bf16( x[16rt + (l&15)][t][kt*32 + (l>>4)*8 + j] )
__global__ void pack_x(const float* __restrict__ X, u16* __restrict__ xp) {
  int tid = blockIdx.x * blockDim.x + threadIdx.x;   // 2097152 threads
  if (tid >= (int)(NB * TT * FF / 8)) return;
  int l  = tid & 63;
  int kt = (tid >> 6) & 31;
  int rt = (tid >> 11) & 3;
  int t  = tid >> 13;                                // 0..255
  int n  = rt * 16 + (l & 15);
  int f  = kt * 32 + (l >> 4) * 8;
  const float* src = X + (size_t)n * TT * FF + (size_t)t * FF + f;
  float4 a = *(const float4*)(src);
  float4 b = *(const float4*)(src + 4);
  u16 tmp[8] = { f2bf(a.x), f2bf(a.y), f2bf(a.z), f2bf(a.w),
                 f2bf(b.x), f2bf(b.y), f2bf(b.z), f2bf(b.w) };
  *(uint4*)(xp + (size_t)((t * 4 + rt) * 32 + kt) * 512 + l * 8) = *(uint4*)tmp;
}

// zero the h double-buffer and the barrier flags (ws is poisoned 0xAA)
__global__ void init_state(u32* __restrict__ hp32, u32* __restrict__ flags) {
  int tid = blockIdx.x * blockDim.x + threadIdx.x;   // 65536 threads
  if (tid < HPACK_SZ / 2) hp32[tid] = 0u;
  if (tid < FLAGS_SZ)     flags[tid] = 0u;
}

__launch_bounds__(256, 1)
__global__ void lstm_main(const u16* __restrict__ wp, const u16* __restrict__ xp,
                          u16* __restrict__ hp, const float* __restrict__ bias,
                          float* __restrict__ z, float* __restrict__ hout,
                          float* __restrict__ memout, u32* flags) {
  const int b   = blockIdx.x;        // 256 blocks, all co-resident (1024 waves)
  const int cgi = b & 63;            // col-group: 16 h-cols
  const int rt  = b >> 6;            // row-tile: 16 batch rows -> barrier group
  const int w   = threadIdx.x >> 6;  // wave = gate index 0..3
  const int l   = threadIdx.x & 63;
  const int ct  = w * 64 + cgi;      // global col-tile 0..255

  const u16* bp = wp + (size_t)ct * 32768 + l * 8;   // 64 kt * 512 per col-tile
  const float bv = bias[ct * 16 + (l & 15)];
  u32* gf = flags + rt * 256;        // this rt-group's 64 flags, stride 4 u32

  __shared__ float gl[4][16][16];

  const int tid = threadIdx.x;
  const int er  = tid >> 4;          // 0..15 epilogue row
  const int ec  = tid & 15;          // 0..15 epilogue col
  const int m   = rt * 16 + er;      // batch row
  const int col = cgi * 16 + ec;     // col within gate [0,1024)
  // hpack write slot for (m, col)
  const int kt2 = col >> 5;
  const int g2  = (col >> 3) & 3;
  const int jj  = col & 7;
  const int l2  = er | (g2 << 4);

  float memv = 0.0f;                 // cell state lives in a register

  for (int t = 0; t < TT; ++t) {
    const int p = t & 1;
    const u16* ax = xp + (size_t)((t * 4 + rt) * 32) * 512 + l * 8;
    const u16* ah = hp + (size_t)((p * 4 + rt) * 32) * 512 + l * 8;

    // ---- x-half of the GEMM first: independent of h, overlaps group skew ----
    f32x4 acc0 = {bv, bv, bv, bv};
    f32x4 acc1 = {0.f, 0.f, 0.f, 0.f};
    #pragma unroll
    for (int kt = 0; kt < 32; kt += 2) {
      bf16x8 a0 = *(const bf16x8*)(ax + (size_t)kt * 512);
      bf16x8 b0 = *(const bf16x8*)(bp + (size_t)kt * 512);
      bf16x8 a1 = *(const bf16x8*)(ax + (size_t)(kt + 1) * 512);
      bf16x8 b1 = *(const bf16x8*)(bp + (size_t)(kt + 1) * 512);
      acc0 = __builtin_amdgcn_mfma_f32_16x16x32_bf16(a0, b0, acc0, 0, 0, 0);
      acc1 = __builtin_amdgcn_mfma_f32_16x16x32_bf16(a1, b1, acc1, 0, 0, 0);
    }

    // ---- wait for h(t): 64-participant rt-group barrier, coalesced poll ----
    if (t != 0) {
      const u32 tgt = (u32)t;
      for (;;) {
        u32 v = __hip_atomic_load(&gf[l * 4], __ATOMIC_RELAXED,
                                  __HIP_MEMORY_SCOPE_AGENT);
        if (l == cgi) v = tgt;       // own arrival is known locally
        if (!__any((int)(v < tgt))) break;
        __builtin_amdgcn_s_sleep(1);
      }
      __builtin_amdgcn_fence(__ATOMIC_ACQUIRE, "agent");
    }

    // ---- h-half of the GEMM ----
    #pragma unroll
    for (int kt = 0; kt < 32; kt += 2) {
      bf16x8 a0 = *(const bf16x8*)(ah + (size_t)kt * 512);
      bf16x8 b0 = *(const bf16x8*)(bp + (size_t)(32 + kt) * 512);
      bf16x8 a1 = *(const bf16x8*)(ah + (size_t)(kt + 1) * 512);
      bf16x8 b1 = *(const bf16x8*)(bp + (size_t)(32 + kt + 1) * 512);
      acc0 = __builtin_amdgcn_mfma_f32_16x16x32_bf16(a0, b0, acc0, 0, 0, 0);
      acc1 = __builtin_amdgcn_mfma_f32_16x16x32_bf16(a1, b1, acc1, 0, 0, 0);
    }

    // C-layout: col = l&15, row = (l>>4)*4 + r  (HW-verified)
    #pragma unroll
    for (int r = 0; r < 4; ++r)
      gl[w][(l >> 4) * 4 + r][l & 15] = acc0[r] + acc1[r];
    __syncthreads();

    // gate combine: one (m,col) element per thread
    float ai = gl[0][er][ec], af = gl[1][er][ec];
    float ao = gl[2][er][ec], ag = gl[3][er][ec];
    float si = 1.f / (1.f + __expf(-ai));
    float sf = 1.f / (1.f + __expf(-af));
    float so = 1.f / (1.f + __expf(-ao));
    float tg = 1.f - 2.f / (__expf(2.f * ag) + 1.f);   // safe tanh
    memv = sf * memv + si * tg;
    float th = 1.f - 2.f / (__expf(2.f * memv) + 1.f); // safe tanh
    float h = so * th;

    z[((size_t)m * TT + t) * HH + col] = h;
    hp[(size_t)(((p ^ 1) * 4 + rt) * 32 + kt2) * 512 + l2 * 8 + jj] = f2bf(h);
    if (t == TT - 1) {
      hout[(size_t)m * HH + col] = h;
      break;                         // no barrier needed after the last step
    }

    // ---- publish h(t+1): drain block stores, one release-store per block ----
    __syncthreads();                 // implies vmcnt(0): hp stores are in L2
    if (tid == 0) {
      __threadfence();               // L2 writeback: h agent-visible
      __hip_atomic_store(&gf[cgi * 4], (u32)(t + 1), __ATOMIC_RELEASE,
                         __HIP_MEMORY_SCOPE_AGENT);
    }
  }
  memout[(size_t)m * HH + col] = memv;
}

extern "C" void kernel_launch(void* const* d_in, const int* in_sizes, int n_in,
                              void* d_out, int out_size, void* d_ws, size_t ws_size,
                              hipStream_t stream) {
  const float* x    = (const float*)d_in[0];
  const float* W    = (const float*)d_in[1];
  const float* bias = (const float*)d_in[2];

  float* z      = (float*)d_out;
  float* hout   = z + (size_t)NB * TT * HH;
  float* memout = hout + (size_t)NB * HH;

  u16* wp = (u16*)d_ws;
  u16* xp = wp + WPACK_SZ;
  u16* hp = xp + XPACK_SZ;
  u32* flags = (u32*)(hp + HPACK_SZ);

  hipLaunchKernelGGL(pack_w, dim3(2048), dim3(256), 0, stream, W, wp);
  hipLaunchKernelGGL(pack_x, dim3(8192), dim3(256), 0, stream, x, xp);
  hipLaunchKernelGGL(init_state, dim3(256), dim3(256), 0, stream, (u32*)hp, flags);

  hipLaunchKernelGGL(lstm_main, dim3(NBLK), dim3(256), 0, stream,
                     wp, xp, hp, bias, z, hout, memout, flags);
}

// Round 5
// 1589.102 us; speedup vs baseline: 6.4110x; 3.8922x over previous
//
#include <hip/hip_runtime.h>

typedef unsigned short u16;
typedef unsigned int   u32;
typedef __attribute__((ext_vector_type(8))) short bf16x8;
typedef __attribute__((ext_vector_type(4))) float f32x4;

#define NB 64
#define TT 256
#define FF 1024
#define HH 1024
#define KK 2048
#define GG 4096
#define NBLK 256

// ws layout in u16 units
#define WPACK_SZ  (KK*GG)                    // 8388608 u16 = 16 MB
#define XPACK_SZ  ((size_t)NB*TT*FF)         // 16777216 u16 = 32 MB
#define HPACK_SZ  (2*4*32*64*8)              // 131072 u16 = 256 KB (double buffer)
#define FLAGS_SZ  (4*64*4)                   // u32: 4 rt-groups x 64 flags, 16B stride

__device__ __forceinline__ u16 f2bf(float f) {
  u32 u = __float_as_uint(f);
  u32 r = (u + 0x7FFFu + ((u >> 16) & 1u)) >> 16;
  return (u16)r;
}

// Pack W [K=2048][G=4096] fp32 -> B-fragment order:
// wp[((ct*64 + kt)*64 + l)*8 + j] = bf16( W[kt*32 + (l>>4)*8 + j][ct*16 + (l&15)] )
__global__ void pack_w(const float* __restrict__ W, u16* __restrict__ wp) {
  int tid = blockIdx.x * blockDim.x + threadIdx.x;   // 524288 threads
  if (tid >= (KK * GG / 16)) return;
  int j  = tid & 7;
  int g  = (tid >> 3) & 3;
  int kt = (tid >> 5) & 63;
  int ct = tid >> 11;                                // 0..255
  int k  = kt * 32 + g * 8 + j;
  const float* src = W + (size_t)k * GG + ct * 16;
  u16* dst = wp + (size_t)(ct * 64 + kt) * 512 + j;
  float4 v0 = *(const float4*)(src + 0);
  float4 v1 = *(const float4*)(src + 4);
  float4 v2 = *(const float4*)(src + 8);
  float4 v3 = *(const float4*)(src + 12);
  float vv[16] = {v0.x,v0.y,v0.z,v0.w, v1.x,v1.y,v1.z,v1.w,
                  v2.x,v2.y,v2.z,v2.w, v3.x,v3.y,v3.z,v3.w};
  #pragma unroll
  for (int c = 0; c < 16; ++c) dst[(size_t)(g * 16 + c) * 8] = f2bf(vv[c]);
}

// Pack x [N][T][F] fp32 -> A-fragment order per (t, rt):
// xp[(((t*4 + rt)*32 + kt)*64 + l)*8 + j] = bf16( x[16rt + (l&15)][t][kt*32 + (l>>4)*8 + j] )
__global__ void pack_x(const float* __restrict__ X, u16* __restrict__ xp) {
  int tid = blockIdx.x * blockDim.x + threadIdx.x;   // 2097152 threads
  if (tid >= (int)(NB * TT * FF / 8)) return;
  int l  = tid & 63;
  int kt = (tid >> 6) & 31;
  int rt = (tid >> 11) & 3;
  int t  = tid >> 13;                                // 0..255
  int n  = rt * 16 + (l & 15);
  int f  = kt * 32 + (l >> 4) * 8;
  const float* src = X + (size_t)n * TT * FF + (size_t)t * FF + f;
  float4 a = *(const float4*)(src);
  float4 b = *(const float4*)(src + 4);
  u16 tmp[8] = { f2bf(a.x), f2bf(a.y), f2bf(a.z), f2bf(a.w),
                 f2bf(b.x), f2bf(b.y), f2bf(b.z), f2bf(b.w) };
  *(uint4*)(xp + (size_t)((t * 4 + rt) * 32 + kt) * 512 + l * 8) = *(uint4*)tmp;
}

// zero barrier flags through the coherence point (ws is poisoned 0xAA; stale
// flags from a previous replay would open barriers spuriously)
__global__ void init_state(u32* __restrict__ flags) {
  int tid = threadIdx.x;
  #pragma unroll
  for (int i = 0; i < 4; ++i)
    __hip_atomic_store(&flags[i * 256 + tid], 0u, __ATOMIC_RELAXED,
                       __HIP_MEMORY_SCOPE_AGENT);
}

__launch_bounds__(256, 1)
__global__ void lstm_main(const u16* __restrict__ wp, const u16* __restrict__ xp,
                          u32* __restrict__ hp32, const float* __restrict__ bias,
                          float* __restrict__ z, float* __restrict__ hout,
                          float* __restrict__ memout, u32* flags) {
  const int b   = blockIdx.x;        // 256 blocks, all co-resident
  const int cgi = b & 63;            // col-group: 16 h-cols
  const int rt  = b >> 6;            // row-tile: 16 batch rows -> barrier group
  const int w   = threadIdx.x >> 6;  // wave = gate index 0..3
  const int l   = threadIdx.x & 63;
  const int ct  = w * 64 + cgi;      // global col-tile 0..255

  const u16* bp = wp + (size_t)ct * 32768 + l * 8;   // 64 kt * 512 per col-tile
  const float bv = bias[ct * 16 + (l & 15)];
  u32* gf = flags + rt * 256;        // this rt-group's 64 flags, stride 4 u32

  __shared__ u32   hs32[8192];       // 32 KB staged h fragments (this rt group)
  __shared__ float gl[4][16][16];    // gate tiles for the combine

  const int tid = threadIdx.x;
  const int er  = tid >> 4;          // 0..15 epilogue row
  const int ec  = tid & 15;          // 0..15 epilogue col
  const int m   = rt * 16 + er;      // batch row
  const int col = cgi * 16 + ec;     // col within gate [0,1024)
  // hp u32 slot for the (even) col pair this thread's pair-store covers
  const int col0 = col & ~1;
  const int kt2  = col0 >> 5;
  const int g2   = (col0 >> 3) & 3;
  const int l2   = er | (g2 << 4);
  const int cbase = kt2 * 256 + l2 * 4 + ((col0 & 7) >> 1);  // u32 units

  float memv = 0.0f;                 // cell state lives in a register

  for (int t = 0; t < TT; ++t) {
    const int p = t & 1;             // h(t) lives in buffer p (written last step)
    const u16* ax = xp + (size_t)((t * 4 + rt) * 32) * 512 + l * 8;

    // ---- x-half of the GEMM: independent of h, overlaps producer skew ----
    f32x4 acc0 = {bv, bv, bv, bv};
    f32x4 acc1 = {0.f, 0.f, 0.f, 0.f};
    #pragma unroll
    for (int kt = 0; kt < 32; kt += 2) {
      bf16x8 a0 = *(const bf16x8*)(ax + (size_t)kt * 512);
      bf16x8 b0 = *(const bf16x8*)(bp + (size_t)kt * 512);
      bf16x8 a1 = *(const bf16x8*)(ax + (size_t)(kt + 1) * 512);
      bf16x8 b1 = *(const bf16x8*)(bp + (size_t)(kt + 1) * 512);
      acc0 = __builtin_amdgcn_mfma_f32_16x16x32_bf16(a0, b0, acc0, 0, 0, 0);
      acc1 = __builtin_amdgcn_mfma_f32_16x16x32_bf16(a1, b1, acc1, 0, 0, 0);
    }

    if (t != 0) {
      // ---- wait for h(t): coalesced poll of the 64 group flags ----
      const u32 tgt = (u32)t;
      for (;;) {
        u32 v = __hip_atomic_load(&gf[l * 4], __ATOMIC_RELAXED,
                                  __HIP_MEMORY_SCOPE_AGENT);
        if (l == cgi) v = tgt;       // own arrival known locally
        if (!__any((int)(v < tgt))) break;
        __builtin_amdgcn_s_sleep(1);
      }

      // ---- copy h fragments to LDS via coherence-point loads (no inv) ----
      const u32* hsrc = hp32 + (size_t)(p * 4 + rt) * 8192;
      u32 tmpv[32];
      #pragma unroll
      for (int i = 0; i < 32; ++i)
        tmpv[i] = __hip_atomic_load(hsrc + i * 256 + tid, __ATOMIC_RELAXED,
                                    __HIP_MEMORY_SCOPE_AGENT);
      #pragma unroll
      for (int i = 0; i < 32; ++i)
        hs32[i * 256 + tid] = tmpv[i];
      __syncthreads();

      // ---- h-half of the GEMM (A fragments from LDS) ----
      const char* hb = (const char*)hs32 + l * 16;
      #pragma unroll
      for (int kt = 0; kt < 32; kt += 2) {
        bf16x8 a0 = *(const bf16x8*)(hb + (size_t)kt * 1024);
        bf16x8 b0 = *(const bf16x8*)(bp + (size_t)(32 + kt) * 512);
        bf16x8 a1 = *(const bf16x8*)(hb + (size_t)(kt + 1) * 1024);
        bf16x8 b1 = *(const bf16x8*)(bp + (size_t)(32 + kt + 1) * 512);
        acc0 = __builtin_amdgcn_mfma_f32_16x16x32_bf16(a0, b0, acc0, 0, 0, 0);
        acc1 = __builtin_amdgcn_mfma_f32_16x16x32_bf16(a1, b1, acc1, 0, 0, 0);
      }
    }

    // C-layout: col = l&15, row = (l>>4)*4 + r  (HW-verified)
    #pragma unroll
    for (int r = 0; r < 4; ++r)
      gl[w][(l >> 4) * 4 + r][l & 15] = acc0[r] + acc1[r];
    __syncthreads();

    // gate combine: one (m,col) element per thread
    float ai = gl[0][er][ec], af = gl[1][er][ec];
    float ao = gl[2][er][ec], ag = gl[3][er][ec];
    float si = 1.f / (1.f + __expf(-ai));
    float sf = 1.f / (1.f + __expf(-af));
    float so = 1.f / (1.f + __expf(-ao));
    float tg = 1.f - 2.f / (__expf(2.f * ag) + 1.f);   // safe tanh
    memv = sf * memv + si * tg;
    float th = 1.f - 2.f / (__expf(2.f * memv) + 1.f); // safe tanh
    float h = so * th;

    z[((size_t)m * TT + t) * HH + col] = h;

    // publish h as bf16 pairs through the coherence point (write-through)
    float hn = __shfl_xor(h, 1);     // partner col's h
    if ((ec & 1) == 0) {
      u32 pair = (u32)f2bf(h) | ((u32)f2bf(hn) << 16);
      __hip_atomic_store(&hp32[(size_t)((p ^ 1) * 4 + rt) * 8192 + cbase], pair,
                         __ATOMIC_RELAXED, __HIP_MEMORY_SCOPE_AGENT);
    }

    if (t == TT - 1) {
      hout[(size_t)m * HH + col] = h;
      break;                         // no publish needed after the last step
    }

    // ---- publish: syncthreads drains vmcnt(0) -> data at coherence point ----
    __syncthreads();
    if (tid == 0)
      __hip_atomic_store(&gf[cgi * 4], (u32)(t + 1), __ATOMIC_RELAXED,
                         __HIP_MEMORY_SCOPE_AGENT);
  }
  memout[(size_t)m * HH + col] = memv;
}

extern "C" void kernel_launch(void* const* d_in, const int* in_sizes, int n_in,
                              void* d_out, int out_size, void* d_ws, size_t ws_size,
                              hipStream_t stream) {
  const float* x    = (const float*)d_in[0];
  const float* W    = (const float*)d_in[1];
  const float* bias = (const float*)d_in[2];

  float* z      = (float*)d_out;
  float* hout   = z + (size_t)NB * TT * HH;
  float* memout = hout + (size_t)NB * HH;

  u16* wp = (u16*)d_ws;
  u16* xp = wp + WPACK_SZ;
  u16* hp = xp + XPACK_SZ;
  u32* flags = (u32*)(hp + HPACK_SZ);

  hipLaunchKernelGGL(pack_w, dim3(2048), dim3(256), 0, stream, W, wp);
  hipLaunchKernelGGL(pack_x, dim3(8192), dim3(256), 0, stream, x, xp);
  hipLaunchKernelGGL(init_state, dim3(1), dim3(256), 0, stream, flags);

  hipLaunchKernelGGL(lstm_main, dim3(NBLK), dim3(256), 0, stream,
                     wp, xp, (u32*)hp, bias, z, hout, memout, flags);
}